// Round 10
// baseline (410.470 us; speedup 1.0000x reference)
//
#include <hip/hip_runtime.h>
#include <math.h>

#define B 2
#define L 2048
#define D 1024
#define H 16
#define HD 64
#define W 32
#define M (B * L)          // 4096
#define KP3 3072           // packed K' = 3*D

typedef unsigned short ushort_t;
typedef short bf16x8 __attribute__((ext_vector_type(8)));
typedef float f32x4 __attribute__((ext_vector_type(4)));

static __device__ __forceinline__ unsigned short f2bf(float f) {
    union { float f; unsigned u; } v; v.f = f;
    unsigned r = v.u + 0x7FFF + ((v.u >> 16) & 1);
    return (unsigned short)(r >> 16);
}
static __device__ __forceinline__ float bf2f(unsigned short h) {
    union { unsigned u; float f; } v; v.u = ((unsigned)h) << 16;
    return v.f;
}
static __device__ __forceinline__ unsigned pk2(unsigned a, unsigned b) {
    return a | (b << 16);
}

// ---------------- packing: fp32 [r][1024] -> A-side [hi | lo | hi] ----------------
__global__ __launch_bounds__(256) void pack_x_kernel(
    const float* __restrict__ src, ushort_t* __restrict__ dst)
{
    const int idx = blockIdx.x * 256 + threadIdx.x;
    const int r = idx >> 7;
    const int c = (idx & 127) << 3;
    const float* p = src + (size_t)r * D + c;
    const float4 f0 = *(const float4*)p;
    const float4 f1 = *(const float4*)(p + 4);
    float f[8] = {f0.x, f0.y, f0.z, f0.w, f1.x, f1.y, f1.z, f1.w};
    unsigned short h[8], lo[8];
#pragma unroll
    for (int i = 0; i < 8; ++i) {
        h[i] = f2bf(f[i]);
        lo[i] = f2bf(f[i] - bf2f(h[i]));
    }
    uint4 hv = make_uint4(pk2(h[0], h[1]), pk2(h[2], h[3]), pk2(h[4], h[5]), pk2(h[6], h[7]));
    uint4 lv = make_uint4(pk2(lo[0], lo[1]), pk2(lo[2], lo[3]), pk2(lo[4], lo[5]), pk2(lo[6], lo[7]));
    ushort_t* d = dst + (size_t)r * KP3 + c;
    *(uint4*)(d)         = hv;
    *(uint4*)(d + D)     = lv;
    *(uint4*)(d + 2 * D) = hv;
}

// ---------------- packing: weights -> B-side [hi | hi | lo] ----------------
__global__ __launch_bounds__(256) void pack_w_kernel(
    const float* __restrict__ s0, const float* __restrict__ s1,
    const float* __restrict__ s2, ushort_t* __restrict__ dst, int nrows)
{
    const int idx = blockIdx.x * 256 + threadIdx.x;
    const int r = idx >> 7;
    if (r >= nrows) return;
    const int c = (idx & 127) << 3;
    const float* src = (r < 1024) ? s0 : ((r < 2048) ? s1 : s2);
    const float* p = src + (size_t)(r & 1023) * D + c;
    const float4 f0 = *(const float4*)p;
    const float4 f1 = *(const float4*)(p + 4);
    float f[8] = {f0.x, f0.y, f0.z, f0.w, f1.x, f1.y, f1.z, f1.w};
    unsigned short h[8], lo[8];
#pragma unroll
    for (int i = 0; i < 8; ++i) {
        h[i] = f2bf(f[i]);
        lo[i] = f2bf(f[i] - bf2f(h[i]));
    }
    uint4 hv = make_uint4(pk2(h[0], h[1]), pk2(h[2], h[3]), pk2(h[4], h[5]), pk2(h[6], h[7]));
    uint4 lv = make_uint4(pk2(lo[0], lo[1]), pk2(lo[2], lo[3]), pk2(lo[4], lo[5]), pk2(lo[6], lo[7]));
    ushort_t* d = dst + (size_t)r * KP3 + c;
    *(uint4*)(d)         = hv;
    *(uint4*)(d + D)     = hv;
    *(uint4*)(d + 2 * D) = lv;
}

// ---------------- conn kernel (tiny) ----------------
__global__ __launch_bounds__(512) void conn_kernel(
    const float* __restrict__ cw1, const float* __restrict__ cw2,
    const float* __restrict__ cw3, float* __restrict__ conn)
{
    __shared__ float vals[H][W];
    const int t = threadIdx.x;
    const int h = t >> 5;
    const int w = t & 31;
    const float pos = (float)w / (float)(W - 1);
    float s = 0.f;
    for (int k = 0; k < 128; ++k) {
        const float a1 = pos * cw1[h * 128 + k];
        const float a3 = pos * cw3[h * 128 + k];
        const float si = a1 / (1.f + expf(-a1));
        s += si * a3 * cw2[h * 128 + k];
    }
    vals[h][w] = s;
    __syncthreads();
    float mx = -1e30f;
    for (int i = 0; i < W; ++i) mx = fmaxf(mx, vals[h][i]);
    float den = 0.f;
    for (int i = 0; i < W; ++i) den += expf(vals[h][i] - mx);
    conn[t] = expf(s - mx) / den;
}

// ---------------- 256x256 8-phase pipelined split-bf16 MFMA GEMM ----------------
// One-phase-ahead register pipeline: ds_reads for phase N+1 issue at phase N;
// counted lgkmcnt overlaps DS drain with MFMA. One barrier per phase.

#define SBAR() __builtin_amdgcn_s_barrier()
#define WAIT_LGKM(n) { asm volatile("s_waitcnt lgkmcnt(" #n ")" ::: "memory"); __builtin_amdgcn_sched_barrier(0); }
#define WAIT_VM(n)   { asm volatile("s_waitcnt vmcnt(" #n ")" ::: "memory"); __builtin_amdgcn_sched_barrier(0); }
#define PRIO1() __builtin_amdgcn_s_setprio(1)
#define PRIO0() __builtin_amdgcn_s_setprio(0)

#define STAGE_A(hh, tt, dd) do { \
    __builtin_amdgcn_global_load_lds((const __attribute__((address_space(1))) void*)(pA##hh##0 + (size_t)(tt) * 64), \
        (__attribute__((address_space(3))) void*)(lds + (dd) * 32768 + (hh) * 8192 + (w * 16 + 0) * 64), 16, 0, 0); \
    __builtin_amdgcn_global_load_lds((const __attribute__((address_space(1))) void*)(pA##hh##1 + (size_t)(tt) * 64), \
        (__attribute__((address_space(3))) void*)(lds + (dd) * 32768 + (hh) * 8192 + (w * 16 + 8) * 64), 16, 0, 0); \
} while (0)

#define STAGE_B(hh, tt, dd) do { \
    __builtin_amdgcn_global_load_lds((const __attribute__((address_space(1))) void*)(pB##hh##0 + (size_t)(tt) * 64), \
        (__attribute__((address_space(3))) void*)(lds + (dd) * 32768 + 16384 + (hh) * 8192 + (w * 16 + 0) * 64), 16, 0, 0); \
    __builtin_amdgcn_global_load_lds((const __attribute__((address_space(1))) void*)(pB##hh##1 + (size_t)(tt) * 64), \
        (__attribute__((address_space(3))) void*)(lds + (dd) * 32768 + 16384 + (hh) * 8192 + (w * 16 + 8) * 64), 16, 0, 0); \
} while (0)

// A quad qm -> set a0/a1 (8 ds_read_b128); B quad qn -> set b0/b1 (4 ds_read_b128)
#define READ_A0(dd) do { \
    _Pragma("unroll") for (int mi = 0; mi < 4; ++mi) { \
        a0[mi][0] = *(const bf16x8*)(lds + (dd) * 32768 + (baseA + mi * 16) * 64 + ch0); \
        a0[mi][1] = *(const bf16x8*)(lds + (dd) * 32768 + (baseA + mi * 16) * 64 + ch1); } \
} while (0)
#define READ_A1(dd) do { \
    _Pragma("unroll") for (int mi = 0; mi < 4; ++mi) { \
        a1[mi][0] = *(const bf16x8*)(lds + (dd) * 32768 + 8192 + (baseA + mi * 16) * 64 + ch0); \
        a1[mi][1] = *(const bf16x8*)(lds + (dd) * 32768 + 8192 + (baseA + mi * 16) * 64 + ch1); } \
} while (0)
#define READ_B0(dd) do { \
    _Pragma("unroll") for (int ni = 0; ni < 2; ++ni) { \
        b0[ni][0] = *(const bf16x8*)(lds + (dd) * 32768 + 16384 + (baseB + ni * 16) * 64 + ch0); \
        b0[ni][1] = *(const bf16x8*)(lds + (dd) * 32768 + 16384 + (baseB + ni * 16) * 64 + ch1); } \
} while (0)
#define READ_B1(dd) do { \
    _Pragma("unroll") for (int ni = 0; ni < 2; ++ni) { \
        b1[ni][0] = *(const bf16x8*)(lds + (dd) * 32768 + 16384 + 8192 + (baseB + ni * 16) * 64 + ch0); \
        b1[ni][1] = *(const bf16x8*)(lds + (dd) * 32768 + 16384 + 8192 + (baseB + ni * 16) * 64 + ch1); } \
} while (0)

#define MMA(qm, qn, aa, bb) do { \
    _Pragma("unroll") for (int mi = 0; mi < 4; ++mi) \
    _Pragma("unroll") for (int ni = 0; ni < 2; ++ni) { \
        acc[(qm)*4+mi][(qn)*2+ni] = __builtin_amdgcn_mfma_f32_16x16x32_bf16(aa[mi][0], bb[ni][0], acc[(qm)*4+mi][(qn)*2+ni], 0, 0, 0); \
        acc[(qm)*4+mi][(qn)*2+ni] = __builtin_amdgcn_mfma_f32_16x16x32_bf16(aa[mi][1], bb[ni][1], acc[(qm)*4+mi][(qn)*2+ni], 0, 0, 0); } \
} while (0)

__global__ __launch_bounds__(512, 2) void gemm8(
    const ushort_t* __restrict__ Ap, const ushort_t* __restrict__ Bp,
    int nkt, int mode, float* __restrict__ outp,
    float* __restrict__ qb, float* __restrict__ kb, float* __restrict__ vb,
    const float* __restrict__ rc, const float* __restrict__ rs)
{
    extern __shared__ short lds[];
    const int tid = threadIdx.x;
    const int w = tid >> 6;
    const int ln = tid & 63;
    const int wr = w >> 2, wc = w & 3;

    // XCD-aware bijective swizzle (nwg % 8 == 0 for both call sites)
    const int gx = gridDim.x;
    const int nwg = gx * gridDim.y;
    int fid = blockIdx.y * gx + blockIdx.x;
    fid = (fid & 7) * (nwg >> 3) + (fid >> 3);
    const int n0 = (fid % gx) * 256;
    const int m0 = (fid / gx) * 256;
    const int z = blockIdx.z;

    if (mode == 2) { Ap += (size_t)z * 1024; Bp += (size_t)z * 1024; }

    const int lchk = ((ln & 7) ^ (ln >> 3)) * 8;
    const ushort_t *pA00, *pA01, *pA10, *pA11, *pB00, *pB01, *pB10, *pB11;
    {
        const int r0 = w * 16 + (ln >> 3);
        const int r1 = w * 16 + 8 + (ln >> 3);
#define GROWA(rl, hh) (m0 + ((rl) & 63) + (((rl) >> 6) * 128) + (hh) * 64)
#define GROWB(rl, hh) (n0 + ((rl) & 31) + (((rl) >> 5) * 64) + (hh) * 32)
        pA00 = Ap + (size_t)GROWA(r0, 0) * KP3 + lchk;
        pA01 = Ap + (size_t)GROWA(r1, 0) * KP3 + lchk;
        pA10 = Ap + (size_t)GROWA(r0, 1) * KP3 + lchk;
        pA11 = Ap + (size_t)GROWA(r1, 1) * KP3 + lchk;
        pB00 = Bp + (size_t)GROWB(r0, 0) * KP3 + lchk;
        pB01 = Bp + (size_t)GROWB(r1, 0) * KP3 + lchk;
        pB10 = Bp + (size_t)GROWB(r0, 1) * KP3 + lchk;
        pB11 = Bp + (size_t)GROWB(r1, 1) * KP3 + lchk;
    }

    const int baseA = wr * 64 + (ln & 15);
    const int baseB = wc * 32 + (ln & 15);
    const int ch0 = ((0 * 4 + (ln >> 4)) ^ (ln & 7)) * 8;
    const int ch1 = ((1 * 4 + (ln >> 4)) ^ (ln & 7)) * 8;

    f32x4 acc[8][4];
#pragma unroll
    for (int i = 0; i < 8; ++i)
#pragma unroll
        for (int j = 0; j < 4; ++j) acc[i][j] = (f32x4){0.f, 0.f, 0.f, 0.f};

    bf16x8 a0[4][2], a1[4][2], b0[2][2], b1[2][2];

    // prologue: t0 full into buf0 (8 loads) + t1 A-h0/B-h0 into buf1 (4 loads)
    STAGE_A(0, 0, 0); STAGE_B(0, 0, 0); STAGE_A(1, 0, 0); STAGE_B(1, 0, 0);
    STAGE_A(0, 1, 1); STAGE_B(0, 1, 1);
    WAIT_VM(4);        // t0's 8 loads landed (t1's 4 stay in flight)
    SBAR();
    READ_A0(0); READ_B0(0);   // 12 reads for ph1's MMA

    const int niters = nkt >> 1;
    for (int it = 0; it < niters; ++it) {
        const int t1 = 2 * it + 1;
        const int t2 = (2 * it + 2 < nkt) ? 2 * it + 2 : 0;   // clamped: keeps count ledger exact
        const int t3 = (2 * it + 3 < nkt) ? 2 * it + 3 : 1;
        // ph1: MMA Q00(buf0) | reads B1(buf0) for ph2
        READ_B1(0); STAGE_A(1, t1, 1);
        WAIT_LGKM(4);  PRIO1(); MMA(0, 0, a0, b0); PRIO0(); WAIT_VM(6); SBAR();
        // ph2: MMA Q01(buf0) | reads A1(buf0)
        READ_A1(0); STAGE_B(1, t1, 1);
        WAIT_LGKM(8);  PRIO1(); MMA(0, 1, a0, b1); PRIO0(); WAIT_VM(6); SBAR();
        // ph3: MMA Q10(buf0) | reads A0(buf1)
        READ_A0(1); STAGE_A(0, t2, 0);
        WAIT_LGKM(8);  PRIO1(); MMA(1, 0, a1, b0); PRIO0(); WAIT_VM(6); SBAR();
        // ph4: MMA Q11(buf0) | reads B0(buf1)
        READ_B0(1); STAGE_B(0, t2, 0);
        WAIT_LGKM(12); PRIO1(); MMA(1, 1, a1, b1); PRIO0(); WAIT_VM(4); SBAR();
        // ph5: MMA Q00(buf1) | reads B1(buf1)
        READ_B1(1); STAGE_A(1, t2, 0);
        WAIT_LGKM(4);  PRIO1(); MMA(0, 0, a0, b0); PRIO0(); WAIT_VM(6); SBAR();
        // ph6: MMA Q01(buf1) | reads A1(buf1)
        READ_A1(1); STAGE_B(1, t2, 0);
        WAIT_LGKM(8);  PRIO1(); MMA(0, 1, a0, b1); PRIO0(); WAIT_VM(6); SBAR();
        // ph7: MMA Q10(buf1) | reads A0(buf0, t2)
        READ_A0(0); STAGE_A(0, t3, 1);
        WAIT_LGKM(8);  PRIO1(); MMA(1, 0, a1, b0); PRIO0(); WAIT_VM(6); SBAR();
        // ph8: MMA Q11(buf1) | reads B0(buf0, t2)
        READ_B0(0); STAGE_B(0, t3, 1);
        WAIT_LGKM(12); PRIO1(); MMA(1, 1, a1, b1); PRIO0(); WAIT_VM(4); SBAR();
    }

    // ---- epilogue: C/D layout col = ln&15, row = (ln>>4)*4 + j ----
    if (mode == 1) {
#pragma unroll
        for (int mf = 0; mf < 8; ++mf)
#pragma unroll
            for (int nf = 0; nf < 4; ++nf)
#pragma unroll
                for (int j = 0; j < 4; ++j) {
                    const int m = m0 + wr * 128 + mf * 16 + (ln >> 4) * 4 + j;
                    const int n = n0 + wc * 64 + nf * 16 + (ln & 15);
                    const int which = n >> 10;
                    float* dst = (which == 0) ? qb : ((which == 1) ? kb : vb);
                    const int bb = m >> 11;
                    const int l = m & (L - 1);
                    const int nn = n & 1023;
                    const int hh = nn >> 6;
                    const int hd = nn & 63;
                    float v = acc[mf][nf][j];
                    if (which < 2) {
                        const int ip = hd >> 1;
                        const float c = rc[l * (HD / 2) + ip];
                        const float s = rs[l * (HD / 2) + ip];
                        const float p = __shfl_xor(v, 1);
                        v = (hd & 1) ? fmaf(p, s, v * c) : fmaf(p, -s, v * c);
                    }
                    dst[(((size_t)(bb * H + hh)) * L + l) * HD + hd] = v;
                }
    } else {
        float* dst = outp + (size_t)z * ((size_t)M * 1024);
#pragma unroll
        for (int mf = 0; mf < 8; ++mf)
#pragma unroll
            for (int nf = 0; nf < 4; ++nf)
#pragma unroll
                for (int j = 0; j < 4; ++j) {
                    const int m = m0 + wr * 128 + mf * 16 + (ln >> 4) * 4 + j;
                    const int n = n0 + wc * 64 + nf * 16 + (ln & 15);
                    dst[(size_t)m * 1024 + n] = acc[mf][nf][j];
                }
    }
}

// ---------------- split-K reduce (3-way) ----------------
__global__ __launch_bounds__(256) void reduce_kernel(
    const float* __restrict__ p, float* __restrict__ out)
{
    const size_t i = ((size_t)blockIdx.x * 256 + threadIdx.x) * 4;
    const float4 a = *(const float4*)(p + i);
    const float4 b = *(const float4*)(p + (size_t)M * 1024 + i);
    const float4 c = *(const float4*)(p + (size_t)2 * M * 1024 + i);
    *(float4*)(out + i) = make_float4(a.x + b.x + c.x, a.y + b.y + c.y,
                                      a.z + b.z + c.z, a.w + b.w + c.w);
}

// ---------------- sliding-window attention (4 waves; fused bf16 pack out) ----------------
#define QT 64
#define KR (QT + W - 1)    // 95
#define KPAD 68

__global__ __launch_bounds__(256) void attn_kernel(
    const float* __restrict__ qb, const float* __restrict__ kb,
    const float* __restrict__ vb, const float* __restrict__ conn,
    ushort_t* __restrict__ aop)
{
    __shared__ float Ks[KR][KPAD];
    __shared__ float Vs[KR][KPAD];   // 51.7 KB -> 3 blocks/CU = 12 waves/CU
    const int tid = threadIdx.x;
    const int r = tid >> 2;          // q-row within tile (0..63)
    const int p = tid & 3;           // hd quarter (16 floats)
    const int l0 = blockIdx.x * QT;
    const int bh = blockIdx.y;
    const int h = bh & (H - 1);
    const int bb = bh >> 4;
    const float* Qg = qb + (size_t)bh * L * HD;
    const float* Kg = kb + (size_t)bh * L * HD;
    const float* Vg = vb + (size_t)bh * L * HD;

    for (int idx = tid; idx < KR * 16; idx += 256) {
        const int rr = idx >> 4;
        const int f4 = (idx & 15) << 2;
        const int lr = l0 - (W - 1) + rr;
        float4 kv = make_float4(0, 0, 0, 0);
        float4 vv = make_float4(0, 0, 0, 0);
        if (lr >= 0) {
            kv = *(const float4*)(Kg + (size_t)lr * HD + f4);
            vv = *(const float4*)(Vg + (size_t)lr * HD + f4);
        }
        *(float4*)&Ks[rr][f4] = kv;
        *(float4*)&Vs[rr][f4] = vv;
    }

    const int l = l0 + r;
    float4 q[4];
#pragma unroll
    for (int i = 0; i < 4; ++i)
        q[i] = *(const float4*)(Qg + (size_t)l * HD + p * 16 + i * 4);

    __syncthreads();

    float sc[W];
#pragma unroll
    for (int w = 0; w < W; ++w) {
        const float* kr = &Ks[r + w][p * 16];
        float s = 0.f;
#pragma unroll
        for (int i = 0; i < 4; ++i) {
            const float4 kv = *(const float4*)(kr + i * 4);
            s = fmaf(q[i].x, kv.x, s);
            s = fmaf(q[i].y, kv.y, s);
            s = fmaf(q[i].z, kv.z, s);
            s = fmaf(q[i].w, kv.w, s);
        }
        s += __shfl_xor(s, 1);
        s += __shfl_xor(s, 2);
        sc[w] = s * 0.125f;
    }

    float mx = -1e30f;
#pragma unroll
    for (int w = 0; w < W; ++w) mx = fmaxf(mx, sc[w]);
    float den = 0.f;
#pragma unroll
    for (int w = 0; w < W; ++w) { sc[w] = expf(sc[w] - mx); den += sc[w]; }
    const float inv = 1.f / den;
    float fsum = 0.f;
#pragma unroll
    for (int w = 0; w < W; ++w) {
        sc[w] = sc[w] * inv * conn[h * W + w];
        fsum += sc[w];
    }
    const float rn = 1.f / (fsum + 1e-9f);

    float4 o[4];
#pragma unroll
    for (int i = 0; i < 4; ++i) o[i] = make_float4(0, 0, 0, 0);
#pragma unroll
    for (int w = 0; w < W; ++w) {
        const float wt = sc[w] * rn;
        const float* vr = &Vs[r + w][p * 16];
#pragma unroll
        for (int i = 0; i < 4; ++i) {
            const float4 vv = *(const float4*)(vr + i * 4);
            o[i].x = fmaf(wt, vv.x, o[i].x);
            o[i].y = fmaf(wt, vv.y, o[i].y);
            o[i].z = fmaf(wt, vv.z, o[i].z);
            o[i].w = fmaf(wt, vv.w, o[i].w);
        }
    }

    // fused bf16 [hi|lo|hi] pack: each 4-lane quad writes full 128B lines
    float f[16];
#pragma unroll
    for (int i = 0; i < 4; ++i) {
        f[4 * i] = o[i].x; f[4 * i + 1] = o[i].y; f[4 * i + 2] = o[i].z; f[4 * i + 3] = o[i].w;
    }
    unsigned short hh16[16], lo16[16];
#pragma unroll
    for (int i = 0; i < 16; ++i) {
        hh16[i] = f2bf(f[i]);
        lo16[i] = f2bf(f[i] - bf2f(hh16[i]));
    }
    uint4 hv0 = make_uint4(pk2(hh16[0], hh16[1]), pk2(hh16[2], hh16[3]), pk2(hh16[4], hh16[5]), pk2(hh16[6], hh16[7]));
    uint4 hv1 = make_uint4(pk2(hh16[8], hh16[9]), pk2(hh16[10], hh16[11]), pk2(hh16[12], hh16[13]), pk2(hh16[14], hh16[15]));
    uint4 lv0 = make_uint4(pk2(lo16[0], lo16[1]), pk2(lo16[2], lo16[3]), pk2(lo16[4], lo16[5]), pk2(lo16[6], lo16[7]));
    uint4 lv1 = make_uint4(pk2(lo16[8], lo16[9]), pk2(lo16[10], lo16[11]), pk2(lo16[12], lo16[13]), pk2(lo16[14], lo16[15]));
    ushort_t* dp = aop + (size_t)(bb * L + l) * KP3 + h * HD + p * 16;
    *(uint4*)(dp)             = hv0;
    *(uint4*)(dp + 8)         = hv1;
    *(uint4*)(dp + D)         = lv0;
    *(uint4*)(dp + D + 8)     = lv1;
    *(uint4*)(dp + 2 * D)     = hv0;
    *(uint4*)(dp + 2 * D + 8) = hv1;
}

// ---------------- launcher ----------------
extern "C" void kernel_launch(void* const* d_in, const int* in_sizes, int n_in,
                              void* d_out, int out_size, void* d_ws, size_t ws_size,
                              hipStream_t stream)
{
    const float* x   = (const float*)d_in[0];
    const float* wq  = (const float*)d_in[1];
    const float* wk  = (const float*)d_in[2];
    const float* wv  = (const float*)d_in[3];
    const float* wo  = (const float*)d_in[4];
    const float* cw1 = (const float*)d_in[5];
    const float* cw2 = (const float*)d_in[6];
    const float* cw3 = (const float*)d_in[7];
    const float* rc  = (const float*)d_in[8];
    const float* rs  = (const float*)d_in[9];
    float* out = (float*)d_out;

    float* ws = (float*)d_ws;
    float* conn = ws;                                  // 1024 floats
    float* qb = ws + 1024;                             // [B*H][L][HD] fp32
    float* kb = qb + (size_t)B * H * L * HD;
    float* vb = kb + (size_t)B * H * L * HD;
    ushort_t* xp    = (ushort_t*)(vb + (size_t)B * H * L * HD);  // [M][3072] bf16 (attn writes packed out here)
    ushort_t* wqkvp = xp + (size_t)M * KP3;            // [3072][3072] bf16
    ushort_t* wop   = wqkvp + (size_t)3072 * KP3;      // [1024][3072] bf16
    float* part = qb;                                  // split-K partials x3 (50.3MB = qb+kb+vb, dead after attn)

    hipFuncSetAttribute((const void*)gemm8, hipFuncAttributeMaxDynamicSharedMemorySize, 131072);

    pack_x_kernel<<<dim3(M * 128 / 256), dim3(256), 0, stream>>>(x, xp);
    pack_w_kernel<<<dim3(3072 * 128 / 256), dim3(256), 0, stream>>>(wq, wk, wv, wqkvp, 3072);
    pack_w_kernel<<<dim3(1024 * 128 / 256), dim3(256), 0, stream>>>(wo, wo, wo, wop, 1024);
    conn_kernel<<<dim3(1), dim3(512), 0, stream>>>(cw1, cw2, cw3, conn);

    gemm8<<<dim3(12, 16, 1), dim3(512), 131072, stream>>>(
        xp, wqkvp, 48, 1, nullptr, qb, kb, vb, rc, rs);

    attn_kernel<<<dim3(L / QT, B * H), dim3(256), 0, stream>>>(qb, kb, vb, conn, xp);

    gemm8<<<dim3(4, 16, 3), dim3(512), 131072, stream>>>(
        xp, wop, 16, 2, part, nullptr, nullptr, nullptr, rc, rs);

    reduce_kernel<<<dim3(M * 1024 / 1024), dim3(256), 0, stream>>>(part, out);
}